// Round 5
// baseline (1145.322 us; speedup 1.0000x reference)
//
#include <hip/hip_runtime.h>

#define NN 12800
#define NE 204800
#define NBLK 256
#define NTHR 1024
#define NGRP ((NBLK * NTHR) / 16)            // 16384 16-lane groups
#define EPG  ((NE + NGRP - 1) / NGRP)        // 13 edges per group

// ---------------- static device scratch (~33 MB) ----------------
__device__ __align__(16) float g_out[NN * 16];   // current node features h
__device__ __align__(16) float g_aggr[NN * 16];  // message accumulator (atomics)
__device__ float g_invd[NN];                     // 1/max(indeg,1)
// A layout: [n][k*20 + j], j=0..15 regular, j=16 bias, 17..19 pad (16B-aligned)
__device__ __align__(16) float g_A[NN * 320];
__device__ __align__(16) float g_ehs[NE * 16];   // edge hidden, src-sorted order
__device__ int g_scnt[NN];                       // src counts -> scan -> cursor
__device__ int g_dcnt[NN];                       // dst in-degree
__device__ int g_sdst[NE];                       // dst per sorted edge
__device__ int g_ssrc[NE];                       // src per sorted edge

// ---- custom grid barrier (sense-reversing, s_sleep backoff) ----
__device__ int g_bar_cnt   = 0;
__device__ int g_bar_sense = 0;

__device__ __forceinline__ void gbar(int* sense) {
    __syncthreads();
    if (threadIdx.x == 0) {
        int s = *sense ^ 1;
        *sense = s;
        __threadfence();  // release: flush this block's writes (agent scope)
        int a = __hip_atomic_fetch_add(&g_bar_cnt, 1, __ATOMIC_ACQ_REL,
                                       __HIP_MEMORY_SCOPE_AGENT);
        if (a == NBLK - 1) {
            __hip_atomic_store(&g_bar_cnt, 0, __ATOMIC_RELAXED,
                               __HIP_MEMORY_SCOPE_AGENT);
            __hip_atomic_store(&g_bar_sense, s, __ATOMIC_RELEASE,
                               __HIP_MEMORY_SCOPE_AGENT);
        } else {
            while (__hip_atomic_load(&g_bar_sense, __ATOMIC_ACQUIRE,
                                     __HIP_MEMORY_SCOPE_AGENT) != s)
                __builtin_amdgcn_s_sleep(16);
        }
        __threadfence();  // acquire: invalidate caches before reading others' data
    }
    __syncthreads();
}

// ============================ fused cooperative path ========================
__global__ __launch_bounds__(NTHR, 4) void k_fused(
    const float* __restrict__ x, const int* __restrict__ ei,
    const float* __restrict__ attr,
    const float* __restrict__ lw, const float* __restrict__ lb,
    const float* __restrict__ w1, const float* __restrict__ b1,
    const float* __restrict__ nn2_w, const float* __restrict__ nn2_b,
    const float* __restrict__ cr, const float* __restrict__ cb,
    const float* __restrict__ wi, const float* __restrict__ wh,
    const float* __restrict__ bi, const float* __restrict__ bh,
    float* __restrict__ out_final)
{
    __shared__ float s_W2t[17 * 256];            // W2 transposed (+bias row 16)
    __shared__ float s_cr[256], s_wiT[768], s_whT[768];
    __shared__ float s_cb[16], s_bi[48], s_bh[48];

    int sense = 0;                               // barrier sense (thread 0's copy used)
    const int t   = threadIdx.x;
    const int gid = blockIdx.x * NTHR + t;
    const int grp = gid >> 4;                    // global 16-lane group id
    const int k   = gid & 15;

    // ---- stage all weights to LDS once ----
    for (int i = t; i < 17 * 256; i += NTHR) {
        int j = i >> 8, r = i & 255;
        s_W2t[i] = (j < 16) ? nn2_w[r * 16 + j] : nn2_b[r];
    }
    if (t < 256) s_cr[t] = cr[t];
    if (t < 768) {
        int row = t >> 4, d = t & 15;
        s_wiT[d * 48 + row] = wi[t];
        s_whT[d * 48 + row] = wh[t];
    }
    if (t < 16) s_cb[t] = cb[t];
    if (t < 48) { s_bi[t] = bi[t]; s_bh[t] = bh[t]; }
    __syncthreads();

    // ---- P0: lin0 + zero aggr/counters (thread per node) ----
    if (gid < NN) {
        int n = gid;
        float x0 = x[n * 3 + 0], x1 = x[n * 3 + 1], x2 = x[n * 3 + 2];
        float v[16];
#pragma unroll
        for (int j = 0; j < 16; ++j) {
            float tt = lb[j] + x0 * lw[j * 3 + 0] + x1 * lw[j * 3 + 1] + x2 * lw[j * 3 + 2];
            v[j] = fmaxf(tt, 0.0f);
        }
#pragma unroll
        for (int j = 0; j < 16; j += 4) {
            *(float4*)(g_out + n * 16 + j)  = make_float4(v[j], v[j + 1], v[j + 2], v[j + 3]);
            *(float4*)(g_aggr + n * 16 + j) = make_float4(0.f, 0.f, 0.f, 0.f);
        }
        g_scnt[n] = 0;
        g_dcnt[n] = 0;
    }
    gbar(&sense);  // 1

    // ---- P1: count src / dst (thread per edge) ----
    if (gid < NE) {
        atomicAdd(&g_scnt[ei[gid]], 1);
        atomicAdd(&g_dcnt[ei[NE + gid]], 1);
    }
    gbar(&sense);  // 2

    // ---- P2: exclusive scan of scnt (single wave, block 0); invd (all) ----
    if (blockIdx.x == 0 && t < 64) {
        const int C = NN / 64;  // 200
        int tot = 0;
        for (int i = 0; i < C; ++i) tot += g_scnt[t * C + i];
        int incl = tot;
#pragma unroll
        for (int off = 1; off < 64; off <<= 1) {
            int v = __shfl_up(incl, off, 64);
            if (t >= off) incl += v;
        }
        int run = incl - tot;
        for (int i = 0; i < C; ++i) {
            int v = g_scnt[t * C + i];
            g_scnt[t * C + i] = run;
            run += v;
        }
    }
    if (gid < NN) g_invd[gid] = 1.0f / fmaxf((float)g_dcnt[gid], 1.0f);
    gbar(&sense);  // 3

    // ---- P3: eh = relu(attr@W1.T+b1), scatter to src-sorted slot ----
    if (gid < NE) {
        int e = gid;
        int s = ei[e], d = ei[NE + e];
        float4 a = *(const float4*)(attr + e * 4);
        float v[16];
#pragma unroll
        for (int j = 0; j < 16; ++j) {
            float tt = b1[j] + a.x * w1[j * 4 + 0] + a.y * w1[j * 4 + 1] +
                       a.z * w1[j * 4 + 2] + a.w * w1[j * 4 + 3];
            v[j] = fmaxf(tt, 0.0f);
        }
        int pos = atomicAdd(&g_scnt[s], 1);
        g_sdst[pos] = d;
        g_ssrc[pos] = s;
#pragma unroll
        for (int j = 0; j < 16; j += 4)
            *(float4*)(g_ehs + pos * 16 + j) = make_float4(v[j], v[j + 1], v[j + 2], v[j + 3]);
    }
    // ---- P4 (same phase): initial A from g_out ----
    if (grp < NN) {
        int n = grp;
        float o[16];
#pragma unroll
        for (int d = 0; d < 16; d += 4) {
            float4 v = *(const float4*)(g_out + n * 16 + d);
            o[d] = v.x; o[d + 1] = v.y; o[d + 2] = v.z; o[d + 3] = v.w;
        }
        float a[17];
#pragma unroll
        for (int j = 0; j < 17; ++j) {
            float acc = 0.0f;
#pragma unroll
            for (int d = 0; d < 16; ++d) acc += o[d] * s_W2t[j * 256 + d * 16 + k];
            a[j] = acc;
        }
        float* Aw = g_A + n * 320 + k * 20;
        *(float4*)(Aw + 0)  = make_float4(a[0], a[1], a[2], a[3]);
        *(float4*)(Aw + 4)  = make_float4(a[4], a[5], a[6], a[7]);
        *(float4*)(Aw + 8)  = make_float4(a[8], a[9], a[10], a[11]);
        *(float4*)(Aw + 12) = make_float4(a[12], a[13], a[14], a[15]);
        Aw[16] = a[16];
    }
    gbar(&sense);  // 4

    // ---- 6 rounds ----
    for (int r = 0; r < 6; ++r) {
        // edge phase: contiguous chunk of src-sorted edges per group
        int e0 = grp * EPG;
        int e1 = e0 + EPG; if (e1 > NE) e1 = NE;
        for (int p = e0; p < e1; ++p) {
            int s = g_ssrc[p];
            int d = g_sdst[p];
            float4 h0 = *(const float4*)(g_ehs + p * 16 + 0);
            float4 h1 = *(const float4*)(g_ehs + p * 16 + 4);
            float4 h2 = *(const float4*)(g_ehs + p * 16 + 8);
            float4 h3 = *(const float4*)(g_ehs + p * 16 + 12);
            const float* Ar = g_A + s * 320 + k * 20;
            float4 a0 = *(const float4*)(Ar + 0);
            float4 a1 = *(const float4*)(Ar + 4);
            float4 a2 = *(const float4*)(Ar + 8);
            float4 a3 = *(const float4*)(Ar + 12);
            float acc = Ar[16];  // bias
            acc += h0.x * a0.x + h0.y * a0.y + h0.z * a0.z + h0.w * a0.w;
            acc += h1.x * a1.x + h1.y * a1.y + h1.z * a1.z + h1.w * a1.w;
            acc += h2.x * a2.x + h2.y * a2.y + h2.z * a2.z + h2.w * a2.w;
            acc += h3.x * a3.x + h3.y * a3.y + h3.z * a3.z + h3.w * a3.w;
            atomicAdd(&g_aggr[d * 16 + k], acc);
        }
        gbar(&sense);  // 5,7,9,11,13,15

        // node phase: group per node, 16-wide shfl
        if (grp < NN) {
            int n = grp;
            float o[16];
#pragma unroll
            for (int d = 0; d < 16; d += 4) {
                float4 v = *(const float4*)(g_out + n * 16 + d);
                o[d] = v.x; o[d + 1] = v.y; o[d + 2] = v.z; o[d + 3] = v.w;
            }
            float ag = g_aggr[n * 16 + k];
            g_aggr[n * 16 + k] = 0.0f;          // re-zero for next round
            float idg = g_invd[n];

            float acc = s_cb[k] + ag * idg;
#pragma unroll
            for (int d = 0; d < 16; ++d) acc += o[d] * s_cr[d * 16 + k];
            float m = fmaxf(acc, 0.0f);

            float ir = s_bi[k], iz = s_bi[16 + k], in_ = s_bi[32 + k];
            float hr = s_bh[k], hz = s_bh[16 + k], hh = s_bh[32 + k];
#pragma unroll
            for (int d = 0; d < 16; ++d) {
                float md = __shfl(m, d, 16);
                ir  += md * s_wiT[d * 48 + k];
                iz  += md * s_wiT[d * 48 + 16 + k];
                in_ += md * s_wiT[d * 48 + 32 + k];
                hr  += o[d] * s_whT[d * 48 + k];
                hz  += o[d] * s_whT[d * 48 + 16 + k];
                hh  += o[d] * s_whT[d * 48 + 32 + k];
            }
            float rg = 1.0f / (1.0f + __expf(-(ir + hr)));
            float z  = 1.0f / (1.0f + __expf(-(iz + hz)));
            float nh = tanhf(in_ + rg * hh);
            float hnew = (1.0f - z) * nh + z * o[k];

            if (r == 5) {
                out_final[n * 16 + k] = hnew;
            } else {
                g_out[n * 16 + k] = hnew;
                float a[17];
#pragma unroll
                for (int j = 0; j < 17; ++j) {
                    float a2 = 0.0f;
#pragma unroll
                    for (int d = 0; d < 16; ++d) {
                        float hd = __shfl(hnew, d, 16);
                        a2 += hd * s_W2t[j * 256 + d * 16 + k];
                    }
                    a[j] = a2;
                }
                float* Aw = g_A + n * 320 + k * 20;
                *(float4*)(Aw + 0)  = make_float4(a[0], a[1], a[2], a[3]);
                *(float4*)(Aw + 4)  = make_float4(a[4], a[5], a[6], a[7]);
                *(float4*)(Aw + 8)  = make_float4(a[8], a[9], a[10], a[11]);
                *(float4*)(Aw + 12) = make_float4(a[12], a[13], a[14], a[15]);
                Aw[16] = a[16];
            }
        }
        gbar(&sense);  // 6,8,10,12,14,16  (total 16: even, sense returns to 0)
    }
}

// ======================= fallback multi-kernel path ========================
__global__ __launch_bounds__(256) void k_setup(const float* __restrict__ x,
                                               const float* __restrict__ lw,
                                               const float* __restrict__ lb) {
    int n = blockIdx.x * 256 + threadIdx.x;
    float x0 = x[n * 3 + 0], x1 = x[n * 3 + 1], x2 = x[n * 3 + 2];
    float v[16];
#pragma unroll
    for (int j = 0; j < 16; ++j) {
        float t = lb[j] + x0 * lw[j * 3 + 0] + x1 * lw[j * 3 + 1] + x2 * lw[j * 3 + 2];
        v[j] = fmaxf(t, 0.0f);
    }
#pragma unroll
    for (int j = 0; j < 16; j += 4) {
        *(float4*)(g_out + n * 16 + j)  = make_float4(v[j], v[j + 1], v[j + 2], v[j + 3]);
        *(float4*)(g_aggr + n * 16 + j) = make_float4(0.f, 0.f, 0.f, 0.f);
    }
    g_scnt[n] = 0;
    g_dcnt[n] = 0;
}

__global__ __launch_bounds__(256) void k_count(const int* __restrict__ ei) {
    int e = blockIdx.x * 256 + threadIdx.x;
    atomicAdd(&g_scnt[ei[e]], 1);
    atomicAdd(&g_dcnt[ei[NE + e]], 1);
}

__global__ __launch_bounds__(256) void k_scan() {
    __shared__ int part[256];
    const int C = NN / 256;
    int t = threadIdx.x;
    int sum = 0;
    for (int i = 0; i < C; ++i) sum += g_scnt[t * C + i];
    part[t] = sum;
    __syncthreads();
    for (int off = 1; off < 256; off <<= 1) {
        int v = (t >= off) ? part[t - off] : 0;
        __syncthreads();
        part[t] += v;
        __syncthreads();
    }
    int run = (t > 0) ? part[t - 1] : 0;
    for (int i = 0; i < C; ++i) {
        int v = g_scnt[t * C + i];
        g_scnt[t * C + i] = run;
        run += v;
    }
    for (int i = t; i < NN; i += 256)
        g_invd[i] = 1.0f / fmaxf((float)g_dcnt[i], 1.0f);
}

__global__ __launch_bounds__(256) void k_scatter(const int* __restrict__ ei,
                                                 const float* __restrict__ attr,
                                                 const float* __restrict__ w1,
                                                 const float* __restrict__ b1) {
    int e = blockIdx.x * 256 + threadIdx.x;
    int s = ei[e], d = ei[NE + e];
    float4 a = *(const float4*)(attr + e * 4);
    float v[16];
#pragma unroll
    for (int j = 0; j < 16; ++j) {
        float t = b1[j] + a.x * w1[j * 4 + 0] + a.y * w1[j * 4 + 1] +
                  a.z * w1[j * 4 + 2] + a.w * w1[j * 4 + 3];
        v[j] = fmaxf(t, 0.0f);
    }
    int pos = atomicAdd(&g_scnt[s], 1);
    g_sdst[pos] = d;
    g_ssrc[pos] = s;
#pragma unroll
    for (int j = 0; j < 16; j += 4)
        *(float4*)(g_ehs + pos * 16 + j) = make_float4(v[j], v[j + 1], v[j + 2], v[j + 3]);
}

__global__ __launch_bounds__(256) void k_expand(const float* __restrict__ nn2_w,
                                                const float* __restrict__ nn2_b) {
    __shared__ float W2t[17 * 256];
    int tid = threadIdx.x;
    for (int m = tid; m < 17 * 256; m += 256) {
        int j = m >> 8, r = m & 255;
        W2t[m] = (j < 16) ? nn2_w[r * 16 + j] : nn2_b[r];
    }
    __syncthreads();
    int grp = tid >> 4, k = tid & 15;
    int n = blockIdx.x * 16 + grp;
    float o[16];
#pragma unroll
    for (int d = 0; d < 16; d += 4) {
        float4 v = *(const float4*)(g_out + n * 16 + d);
        o[d] = v.x; o[d + 1] = v.y; o[d + 2] = v.z; o[d + 3] = v.w;
    }
    float a[17];
#pragma unroll
    for (int j = 0; j < 17; ++j) {
        float acc = 0.0f;
#pragma unroll
        for (int d = 0; d < 16; ++d) acc += o[d] * W2t[j * 256 + d * 16 + k];
        a[j] = acc;
    }
    float* Aw = g_A + n * 320 + k * 20;
    *(float4*)(Aw + 0)  = make_float4(a[0], a[1], a[2], a[3]);
    *(float4*)(Aw + 4)  = make_float4(a[4], a[5], a[6], a[7]);
    *(float4*)(Aw + 8)  = make_float4(a[8], a[9], a[10], a[11]);
    *(float4*)(Aw + 12) = make_float4(a[12], a[13], a[14], a[15]);
    Aw[16] = a[16];
}

__global__ __launch_bounds__(256) void k_edge() {
    int tid = threadIdx.x;
    int grp = tid >> 4, k = tid & 15;
    int p = blockIdx.x * 16 + grp;
    int s = g_ssrc[p];
    int d = g_sdst[p];
    float4 h0 = *(const float4*)(g_ehs + p * 16 + 0);
    float4 h1 = *(const float4*)(g_ehs + p * 16 + 4);
    float4 h2 = *(const float4*)(g_ehs + p * 16 + 8);
    float4 h3 = *(const float4*)(g_ehs + p * 16 + 12);
    const float* Ar = g_A + s * 320 + k * 20;
    float4 a0 = *(const float4*)(Ar + 0);
    float4 a1 = *(const float4*)(Ar + 4);
    float4 a2 = *(const float4*)(Ar + 8);
    float4 a3 = *(const float4*)(Ar + 12);
    float acc = Ar[16];
    acc += h0.x * a0.x + h0.y * a0.y + h0.z * a0.z + h0.w * a0.w;
    acc += h1.x * a1.x + h1.y * a1.y + h1.z * a1.z + h1.w * a1.w;
    acc += h2.x * a2.x + h2.y * a2.y + h2.z * a2.z + h2.w * a2.w;
    acc += h3.x * a3.x + h3.y * a3.y + h3.z * a3.z + h3.w * a3.w;
    atomicAdd(&g_aggr[d * 16 + k], acc);
}

__global__ __launch_bounds__(256) void k_nodeA(const float* __restrict__ cr,
                                               const float* __restrict__ cb,
                                               const float* __restrict__ wi,
                                               const float* __restrict__ wh,
                                               const float* __restrict__ bi,
                                               const float* __restrict__ bh,
                                               const float* __restrict__ nn2_w,
                                               const float* __restrict__ nn2_b,
                                               float* __restrict__ out_final,
                                               int last) {
    __shared__ float s_cr[256], s_wiT[768], s_whT[768], s_W2t[17 * 256];
    __shared__ float s_cb[16], s_bi[48], s_bh[48], s_m[256];
    int t = threadIdx.x;
    s_cr[t] = cr[t];
    for (int i = t; i < 768; i += 256) {
        int row = i >> 4, d = i & 15;
        s_wiT[d * 48 + row] = wi[i];
        s_whT[d * 48 + row] = wh[i];
    }
    for (int i = t; i < 17 * 256; i += 256) {
        int j = i >> 8, r = i & 255;
        s_W2t[i] = (j < 16) ? nn2_w[r * 16 + j] : nn2_b[r];
    }
    if (t < 16) s_cb[t] = cb[t];
    if (t < 48) { s_bi[t] = bi[t]; s_bh[t] = bh[t]; }
    __syncthreads();

    int grp = t >> 4, k = t & 15;
    int n = blockIdx.x * 16 + grp;
    float o[16];
#pragma unroll
    for (int d = 0; d < 16; d += 4) {
        float4 v = *(const float4*)(g_out + n * 16 + d);
        o[d] = v.x; o[d + 1] = v.y; o[d + 2] = v.z; o[d + 3] = v.w;
    }
    float ag = g_aggr[n * 16 + k];
    g_aggr[n * 16 + k] = 0.0f;
    float idg = g_invd[n];

    float acc = s_cb[k] + ag * idg;
#pragma unroll
    for (int d = 0; d < 16; ++d) acc += o[d] * s_cr[d * 16 + k];
    float m = fmaxf(acc, 0.0f);
    s_m[grp * 16 + k] = m;
    __syncthreads();

    float md[16];
#pragma unroll
    for (int d = 0; d < 16; ++d) md[d] = s_m[grp * 16 + d];
    float ir = s_bi[k], iz = s_bi[16 + k], in_ = s_bi[32 + k];
    float hr = s_bh[k], hz = s_bh[16 + k], hh = s_bh[32 + k];
#pragma unroll
    for (int d = 0; d < 16; ++d) {
        ir  += md[d] * s_wiT[d * 48 + k];
        iz  += md[d] * s_wiT[d * 48 + 16 + k];
        in_ += md[d] * s_wiT[d * 48 + 32 + k];
        hr  += o[d] * s_whT[d * 48 + k];
        hz  += o[d] * s_whT[d * 48 + 16 + k];
        hh  += o[d] * s_whT[d * 48 + 32 + k];
    }
    float r = 1.0f / (1.0f + __expf(-(ir + hr)));
    float z = 1.0f / (1.0f + __expf(-(iz + hz)));
    float nh = tanhf(in_ + r * hh);
    float hnew = (1.0f - z) * nh + z * o[k];

    if (last) {
        out_final[n * 16 + k] = hnew;
    } else {
        g_out[n * 16 + k] = hnew;
        __syncthreads();
        s_m[grp * 16 + k] = hnew;
        __syncthreads();
        float on[16];
#pragma unroll
        for (int d = 0; d < 16; ++d) on[d] = s_m[grp * 16 + d];
        float a[17];
#pragma unroll
        for (int j = 0; j < 17; ++j) {
            float a2 = 0.0f;
#pragma unroll
            for (int d = 0; d < 16; ++d) a2 += on[d] * s_W2t[j * 256 + d * 16 + k];
            a[j] = a2;
        }
        float* Aw = g_A + n * 320 + k * 20;
        *(float4*)(Aw + 0)  = make_float4(a[0], a[1], a[2], a[3]);
        *(float4*)(Aw + 4)  = make_float4(a[4], a[5], a[6], a[7]);
        *(float4*)(Aw + 8)  = make_float4(a[8], a[9], a[10], a[11]);
        *(float4*)(Aw + 12) = make_float4(a[12], a[13], a[14], a[15]);
        Aw[16] = a[16];
    }
}

extern "C" void kernel_launch(void* const* d_in, const int* in_sizes, int n_in,
                              void* d_out, int out_size, void* d_ws, size_t ws_size,
                              hipStream_t stream) {
    const float* x         = (const float*)d_in[0];
    const int*   ei        = (const int*)d_in[1];
    const float* edge_attr = (const float*)d_in[2];
    const float* lin0_w    = (const float*)d_in[3];
    const float* lin0_b    = (const float*)d_in[4];
    const float* nn1_w     = (const float*)d_in[5];
    const float* nn1_b     = (const float*)d_in[6];
    const float* nn2_w     = (const float*)d_in[7];
    const float* nn2_b     = (const float*)d_in[8];
    const float* conv_root = (const float*)d_in[9];
    const float* conv_bias = (const float*)d_in[10];
    const float* gru_w_ih  = (const float*)d_in[11];
    const float* gru_w_hh  = (const float*)d_in[12];
    const float* gru_b_ih  = (const float*)d_in[13];
    const float* gru_b_hh  = (const float*)d_in[14];
    float* out = (float*)d_out;

    void* args[] = {
        (void*)&x, (void*)&ei, (void*)&edge_attr,
        (void*)&lin0_w, (void*)&lin0_b,
        (void*)&nn1_w, (void*)&nn1_b,
        (void*)&nn2_w, (void*)&nn2_b,
        (void*)&conv_root, (void*)&conv_bias,
        (void*)&gru_w_ih, (void*)&gru_w_hh,
        (void*)&gru_b_ih, (void*)&gru_b_hh,
        (void*)&out,
    };
    hipError_t err = hipLaunchCooperativeKernel((const void*)k_fused, dim3(NBLK),
                                                dim3(NTHR), args, 0, stream);
    if (err != hipSuccess) {
        // fallback: verified multi-kernel path (identical math)
        k_setup<<<NN / 256, 256, 0, stream>>>(x, lin0_w, lin0_b);
        k_count<<<NE / 256, 256, 0, stream>>>(ei);
        k_scan<<<1, 256, 0, stream>>>();
        k_scatter<<<NE / 256, 256, 0, stream>>>(ei, edge_attr, nn1_w, nn1_b);
        k_expand<<<NN / 16, 256, 0, stream>>>(nn2_w, nn2_b);
        for (int r = 0; r < 6; ++r) {
            k_edge<<<NE / 16, 256, 0, stream>>>();
            k_nodeA<<<NN / 16, 256, 0, stream>>>(conv_root, conv_bias, gru_w_ih,
                                                 gru_w_hh, gru_b_ih, gru_b_hh,
                                                 nn2_w, nn2_b, out, r == 5 ? 1 : 0);
        }
    }
}

// Round 6
// 361.981 us; speedup vs baseline: 3.1640x; 3.1640x over previous
//
#include <hip/hip_runtime.h>

#define NN 12800
#define NE 204800

// ---------------- static device scratch (~15 MB) ----------------
__device__ __align__(16) float g_outA[NN * 16];  // node features ping
__device__ __align__(16) float g_outB[NN * 16];  // node features pong
__device__ __align__(16) float g_ehs[NE * 16];   // edge hidden, DST-sorted order
__device__ int g_src[NE];                        // src per dst-sorted edge
__device__ int g_dcnt[NN];                       // in-degree (CSR segment length)
__device__ int g_rowp[NN];                       // CSR row start (exclusive scan)
__device__ int g_cur[NN];                        // scatter cursor (copy of rowp)

// ---- S0: out0 = relu(x @ lin0_w.T + b); zero dcnt ----
__global__ __launch_bounds__(256) void k_setup(const float* __restrict__ x,
                                               const float* __restrict__ lw,
                                               const float* __restrict__ lb) {
    int n = blockIdx.x * 256 + threadIdx.x;
    float x0 = x[n * 3 + 0], x1 = x[n * 3 + 1], x2 = x[n * 3 + 2];
    float v[16];
#pragma unroll
    for (int j = 0; j < 16; ++j) {
        float t = lb[j] + x0 * lw[j * 3 + 0] + x1 * lw[j * 3 + 1] + x2 * lw[j * 3 + 2];
        v[j] = fmaxf(t, 0.0f);
    }
#pragma unroll
    for (int j = 0; j < 16; j += 4)
        *(float4*)(g_outA + n * 16 + j) = make_float4(v[j], v[j + 1], v[j + 2], v[j + 3]);
    g_dcnt[n] = 0;
}

// ---- S1: count dst occurrences ----
__global__ __launch_bounds__(256) void k_count(const int* __restrict__ ei) {
    int e = blockIdx.x * 256 + threadIdx.x;
    atomicAdd(&g_dcnt[ei[NE + e]], 1);
}

// ---- S2: exclusive scan dcnt -> rowp, cur ----
__global__ __launch_bounds__(256) void k_scan() {
    __shared__ int part[256];
    const int C = NN / 256;  // 50
    int t = threadIdx.x;
    int sum = 0;
    for (int i = 0; i < C; ++i) sum += g_dcnt[t * C + i];
    part[t] = sum;
    __syncthreads();
    for (int off = 1; off < 256; off <<= 1) {
        int v = (t >= off) ? part[t - off] : 0;
        __syncthreads();
        part[t] += v;
        __syncthreads();
    }
    int run = (t > 0) ? part[t - 1] : 0;
    for (int i = 0; i < C; ++i) {
        int idx = t * C + i;
        g_rowp[idx] = run;
        g_cur[idx] = run;
        run += g_dcnt[idx];
    }
}

// ---- S3: eh = relu(attr @ nn1_w.T + b1); scatter into dst-sorted slot ----
__global__ __launch_bounds__(256) void k_scatter(const int* __restrict__ ei,
                                                 const float* __restrict__ attr,
                                                 const float* __restrict__ w1,
                                                 const float* __restrict__ b1) {
    int e = blockIdx.x * 256 + threadIdx.x;
    int s = ei[e], d = ei[NE + e];
    float4 a = *(const float4*)(attr + e * 4);
    float v[16];
#pragma unroll
    for (int j = 0; j < 16; ++j) {
        float t = b1[j] + a.x * w1[j * 4 + 0] + a.y * w1[j * 4 + 1] +
                  a.z * w1[j * 4 + 2] + a.w * w1[j * 4 + 3];
        v[j] = fmaxf(t, 0.0f);
    }
    int pos = atomicAdd(&g_cur[d], 1);
    g_src[pos] = s;
#pragma unroll
    for (int j = 0; j < 16; j += 4)
        *(float4*)(g_ehs + pos * 16 + j) = make_float4(v[j], v[j + 1], v[j + 2], v[j + 3]);
}

// ---- one full message-passing round, one dispatch, no atomics ----
// 16-lane group per dst node n:
//   G[j][d] = sum_{e->n} eh[e,j]*out[src_e,d]  (lane k holds column d=k; row 16 = sum out)
//   aggr[k] = sum_{j,d} G[j][d]*W2e[j][d][k]   (W2e row 16 = nn2_b term)
//   m = relu(aggr/deg + out[n]@conv_root + cb); GRU -> out_nxt[n]
__global__ __launch_bounds__(256) void k_round(const float* __restrict__ nn2_w,
                                               const float* __restrict__ nn2_b,
                                               const float* __restrict__ cr,
                                               const float* __restrict__ cb,
                                               const float* __restrict__ wi,
                                               const float* __restrict__ wh,
                                               const float* __restrict__ bi,
                                               const float* __restrict__ bh,
                                               float* __restrict__ out_final,
                                               int flip, int last) {
    __shared__ float s_W2e[17 * 256];            // [j][d*16+k], j=16 -> nn2_b
    __shared__ float s_cr[256], s_wiT[768], s_whT[768];
    __shared__ float s_cb[16], s_bi[48], s_bh[48];
    __shared__ float s_G[16][272];               // per-group staging (17x16)

    int t = threadIdx.x;
    for (int i = t; i < 17 * 256; i += 256) {
        int j = i >> 8, r = i & 255;
        s_W2e[i] = (j < 16) ? nn2_w[r * 16 + j] : nn2_b[r];
    }
    s_cr[t] = cr[t];                             // [d*16+k]
    for (int i = t; i < 768; i += 256) {
        int row = i >> 4, d = i & 15;
        s_wiT[d * 48 + row] = wi[i];
        s_whT[d * 48 + row] = wh[i];
    }
    if (t < 16) s_cb[t] = cb[t];
    if (t < 48) { s_bi[t] = bi[t]; s_bh[t] = bh[t]; }
    __syncthreads();

    const float* cur = flip ? g_outB : g_outA;
    float*       nxt = flip ? g_outA : g_outB;

    int grp = t >> 4, k = t & 15;
    int n = blockIdx.x * 16 + grp;
    int start = g_rowp[n];
    int deg   = g_dcnt[n];

    // ---- G accumulation over in-edges ----
    float Gk[17];
#pragma unroll
    for (int j = 0; j < 17; ++j) Gk[j] = 0.0f;
    for (int q = 0; q < deg; ++q) {
        int p = start + q;
        int s = g_src[p];                        // broadcast (same addr per group)
        float ok = cur[s * 16 + k];              // coalesced 64B per group
        float4 e0 = *(const float4*)(g_ehs + p * 16 + 0);   // broadcast
        float4 e1 = *(const float4*)(g_ehs + p * 16 + 4);
        float4 e2 = *(const float4*)(g_ehs + p * 16 + 8);
        float4 e3 = *(const float4*)(g_ehs + p * 16 + 12);
        Gk[0]  += e0.x * ok; Gk[1]  += e0.y * ok; Gk[2]  += e0.z * ok; Gk[3]  += e0.w * ok;
        Gk[4]  += e1.x * ok; Gk[5]  += e1.y * ok; Gk[6]  += e1.z * ok; Gk[7]  += e1.w * ok;
        Gk[8]  += e2.x * ok; Gk[9]  += e2.y * ok; Gk[10] += e2.z * ok; Gk[11] += e2.w * ok;
        Gk[12] += e3.x * ok; Gk[13] += e3.y * ok; Gk[14] += e3.z * ok; Gk[15] += e3.w * ok;
        Gk[16] += ok;                            // bias row (eh == 1)
    }

    // ---- stage G to LDS (same wave: in-order LDS pipe, no barrier needed) ----
    float* Gs = &s_G[grp][0];
#pragma unroll
    for (int j = 0; j < 17; ++j) Gs[j * 16 + k] = Gk[j];

    // ---- contraction with W2e ----
    float acc = 0.0f;
#pragma unroll 1
    for (int j = 0; j < 17; ++j) {
#pragma unroll
        for (int d = 0; d < 16; ++d)
            acc += Gs[j * 16 + d] * s_W2e[j * 256 + d * 16 + k];
    }
    float invd = 1.0f / (float)(deg > 0 ? deg : 1);
    float a_k = acc * invd;

    // ---- node update ----
    float o[16];
#pragma unroll
    for (int d = 0; d < 16; d += 4) {
        float4 v = *(const float4*)(cur + n * 16 + d);      // broadcast per group
        o[d] = v.x; o[d + 1] = v.y; o[d + 2] = v.z; o[d + 3] = v.w;
    }
    float mcc = s_cb[k] + a_k;
#pragma unroll
    for (int d = 0; d < 16; ++d) mcc += o[d] * s_cr[d * 16 + k];
    float m = fmaxf(mcc, 0.0f);

    Gs[k] = m;                                   // reuse staging (same-wave order)
    float md[16];
#pragma unroll
    for (int d = 0; d < 16; ++d) md[d] = Gs[d];

    float ir = s_bi[k], iz = s_bi[16 + k], in_ = s_bi[32 + k];
    float hr = s_bh[k], hz = s_bh[16 + k], hh = s_bh[32 + k];
#pragma unroll
    for (int d = 0; d < 16; ++d) {
        ir  += md[d] * s_wiT[d * 48 + k];
        iz  += md[d] * s_wiT[d * 48 + 16 + k];
        in_ += md[d] * s_wiT[d * 48 + 32 + k];
        hr  += o[d] * s_whT[d * 48 + k];
        hz  += o[d] * s_whT[d * 48 + 16 + k];
        hh  += o[d] * s_whT[d * 48 + 32 + k];
    }
    float rg = 1.0f / (1.0f + __expf(-(ir + hr)));
    float z  = 1.0f / (1.0f + __expf(-(iz + hz)));
    float nh = tanhf(in_ + rg * hh);
    float hnew = (1.0f - z) * nh + z * o[k];

    if (last) out_final[n * 16 + k] = hnew;
    else      nxt[n * 16 + k] = hnew;
}

extern "C" void kernel_launch(void* const* d_in, const int* in_sizes, int n_in,
                              void* d_out, int out_size, void* d_ws, size_t ws_size,
                              hipStream_t stream) {
    const float* x         = (const float*)d_in[0];
    const int*   ei        = (const int*)d_in[1];
    const float* edge_attr = (const float*)d_in[2];
    const float* lin0_w    = (const float*)d_in[3];
    const float* lin0_b    = (const float*)d_in[4];
    const float* nn1_w     = (const float*)d_in[5];
    const float* nn1_b     = (const float*)d_in[6];
    const float* nn2_w     = (const float*)d_in[7];
    const float* nn2_b     = (const float*)d_in[8];
    const float* conv_root = (const float*)d_in[9];
    const float* conv_bias = (const float*)d_in[10];
    const float* gru_w_ih  = (const float*)d_in[11];
    const float* gru_w_hh  = (const float*)d_in[12];
    const float* gru_b_ih  = (const float*)d_in[13];
    const float* gru_b_hh  = (const float*)d_in[14];
    float* out = (float*)d_out;

    k_setup<<<NN / 256, 256, 0, stream>>>(x, lin0_w, lin0_b);
    k_count<<<NE / 256, 256, 0, stream>>>(ei);
    k_scan<<<1, 256, 0, stream>>>();
    k_scatter<<<NE / 256, 256, 0, stream>>>(ei, edge_attr, nn1_w, nn1_b);

    for (int r = 0; r < 6; ++r) {
        k_round<<<NN / 16, 256, 0, stream>>>(nn2_w, nn2_b, conv_root, conv_bias,
                                             gru_w_ih, gru_w_hh, gru_b_ih, gru_b_hh,
                                             out, r & 1, r == 5 ? 1 : 0);
    }
}

// Round 7
// 279.844 us; speedup vs baseline: 4.0927x; 1.2935x over previous
//
#include <hip/hip_runtime.h>

#define NN 12800
#define NE 204800

// ---------------- static device scratch (~14 MB) ----------------
__device__ __align__(16) float g_outA[NN * 16];  // node features ping
__device__ __align__(16) float g_outB[NN * 16];  // node features pong
__device__ __align__(16) float g_ehs[NE * 16];   // edge hidden, DST-sorted order
__device__ int g_src[NE];                        // src per dst-sorted edge
__device__ int g_dcnt[NN];                       // in-degree (CSR segment length)
__device__ int g_rowp[NN];                       // CSR row start (exclusive scan)
__device__ int g_cur[NN];                        // scatter cursor (copy of rowp)

// ---- S0: out0 = relu(x @ lin0_w.T + b); zero dcnt ----
__global__ __launch_bounds__(256) void k_setup(const float* __restrict__ x,
                                               const float* __restrict__ lw,
                                               const float* __restrict__ lb) {
    int n = blockIdx.x * 256 + threadIdx.x;
    float x0 = x[n * 3 + 0], x1 = x[n * 3 + 1], x2 = x[n * 3 + 2];
    float v[16];
#pragma unroll
    for (int j = 0; j < 16; ++j) {
        float t = lb[j] + x0 * lw[j * 3 + 0] + x1 * lw[j * 3 + 1] + x2 * lw[j * 3 + 2];
        v[j] = fmaxf(t, 0.0f);
    }
#pragma unroll
    for (int j = 0; j < 16; j += 4)
        *(float4*)(g_outA + n * 16 + j) = make_float4(v[j], v[j + 1], v[j + 2], v[j + 3]);
    g_dcnt[n] = 0;
}

// ---- S1: count dst occurrences ----
__global__ __launch_bounds__(256) void k_count(const int* __restrict__ ei) {
    int e = blockIdx.x * 256 + threadIdx.x;
    atomicAdd(&g_dcnt[ei[NE + e]], 1);
}

// ---- S2: exclusive scan dcnt -> rowp, cur ----
__global__ __launch_bounds__(256) void k_scan() {
    __shared__ int part[256];
    const int C = NN / 256;  // 50
    int t = threadIdx.x;
    int sum = 0;
    for (int i = 0; i < C; ++i) sum += g_dcnt[t * C + i];
    part[t] = sum;
    __syncthreads();
    for (int off = 1; off < 256; off <<= 1) {
        int v = (t >= off) ? part[t - off] : 0;
        __syncthreads();
        part[t] += v;
        __syncthreads();
    }
    int run = (t > 0) ? part[t - 1] : 0;
    for (int i = 0; i < C; ++i) {
        int idx = t * C + i;
        g_rowp[idx] = run;
        g_cur[idx] = run;
        run += g_dcnt[idx];
    }
}

// ---- S3: eh = relu(attr @ nn1_w.T + b1); scatter into dst-sorted slot ----
__global__ __launch_bounds__(256) void k_scatter(const int* __restrict__ ei,
                                                 const float* __restrict__ attr,
                                                 const float* __restrict__ w1,
                                                 const float* __restrict__ b1) {
    int e = blockIdx.x * 256 + threadIdx.x;
    int s = ei[e], d = ei[NE + e];
    float4 a = *(const float4*)(attr + e * 4);
    float v[16];
#pragma unroll
    for (int j = 0; j < 16; ++j) {
        float t = b1[j] + a.x * w1[j * 4 + 0] + a.y * w1[j * 4 + 1] +
                  a.z * w1[j * 4 + 2] + a.w * w1[j * 4 + 3];
        v[j] = fmaxf(t, 0.0f);
    }
    int pos = atomicAdd(&g_cur[d], 1);
    g_src[pos] = s;
#pragma unroll
    for (int j = 0; j < 16; j += 4)
        *(float4*)(g_ehs + pos * 16 + j) = make_float4(v[j], v[j + 1], v[j + 2], v[j + 3]);
}

// ---- one round, one dispatch, no atomics. 256 thr = 8 nodes x 32 lanes. ----
// lane: h = (t>>4)&1 (edge-half), k = t&15 (feature / d-column).
//   G[j][d] = sum_{e->n} eh[e,j]*out[src_e,d]; lane k holds column d=k (row16 = sum out)
//   halves split edges (q = h, h+2, ...), combined via shfl_xor(16)
//   contraction: lane d=k computes T[k'] = sum_j G[j][k]*W2[(k*16+k')*16+j] for 8 k'
//   (half h covers k' in [8h, 8h+8)), then 4-stage xor butterfly sums over d.
__global__ __launch_bounds__(256) void k_round(const float* __restrict__ nn2_w,
                                               const float* __restrict__ nn2_b,
                                               const float* __restrict__ cr,
                                               const float* __restrict__ cb,
                                               const float* __restrict__ wi,
                                               const float* __restrict__ wh,
                                               const float* __restrict__ bi,
                                               const float* __restrict__ bh,
                                               float* __restrict__ out_final,
                                               int flip, int last) {
    // s_W2[d*260 + k'*16 + j] = nn2_w[(d*16+k')*16 + j]  (stride 260: bank-spread)
    __shared__ float s_W2[16 * 260];
    __shared__ float s_b2[16 * 17];              // [d*17+k'] = nn2_b[d*16+k']
    __shared__ float s_cr[256], s_wiT[768], s_whT[768];
    __shared__ float s_cb[16], s_bi[48], s_bh[48];

    int t = threadIdx.x;
    // coalesced staging
    for (int i = t; i < 4096; i += 256) {
        float v = nn2_w[i];
        int j = i & 15, m = i >> 4, kp = m & 15, d = m >> 4;
        s_W2[d * 260 + kp * 16 + j] = v;
    }
    { int d = t >> 4, kp = t & 15; s_b2[d * 17 + kp] = nn2_b[t]; }
    s_cr[t] = cr[t];                             // [d*16+k]
    for (int i = t; i < 768; i += 256) {
        int row = i >> 4, d = i & 15;
        s_wiT[d * 48 + row] = wi[i];
        s_whT[d * 48 + row] = wh[i];
    }
    if (t < 16) s_cb[t] = cb[t];
    if (t < 48) { s_bi[t] = bi[t]; s_bh[t] = bh[t]; }
    __syncthreads();

    const float* cur = flip ? g_outB : g_outA;
    float*       nxt = flip ? g_outA : g_outB;

    const int h = (t >> 4) & 1, k = t & 15;
    const int n = blockIdx.x * 8 + (t >> 5);
    const int start = g_rowp[n];
    const int deg   = g_dcnt[n];

    // ---- G accumulation: half h takes edges q = h, h+2, ... ----
    float Gk[17];
#pragma unroll
    for (int j = 0; j < 17; ++j) Gk[j] = 0.0f;
#pragma unroll 2
    for (int q = h; q < deg; q += 2) {
        int p = start + q;
        int s = g_src[p];                        // broadcast within half
        float ok = cur[s * 16 + k];              // 64B coalesced per half
        float4 e0 = *(const float4*)(g_ehs + p * 16 + 0);
        float4 e1 = *(const float4*)(g_ehs + p * 16 + 4);
        float4 e2 = *(const float4*)(g_ehs + p * 16 + 8);
        float4 e3 = *(const float4*)(g_ehs + p * 16 + 12);
        Gk[0]  += e0.x * ok; Gk[1]  += e0.y * ok; Gk[2]  += e0.z * ok; Gk[3]  += e0.w * ok;
        Gk[4]  += e1.x * ok; Gk[5]  += e1.y * ok; Gk[6]  += e1.z * ok; Gk[7]  += e1.w * ok;
        Gk[8]  += e2.x * ok; Gk[9]  += e2.y * ok; Gk[10] += e2.z * ok; Gk[11] += e2.w * ok;
        Gk[12] += e3.x * ok; Gk[13] += e3.y * ok; Gk[14] += e3.z * ok; Gk[15] += e3.w * ok;
        Gk[16] += ok;                            // bias row (eh == 1)
    }
    // combine the two halves: both end up with full G column
#pragma unroll
    for (int j = 0; j < 17; ++j) Gk[j] += __shfl_xor(Gk[j], 16);

    // ---- contraction: 8 outputs per lane, butterfly over d ----
    float T[8];
    const float* wbase = s_W2 + k * 260;
#pragma unroll
    for (int i = 0; i < 8; ++i) {
        int kp = h * 8 + i;
        const float* w = wbase + kp * 16;
        float acc = Gk[16] * s_b2[k * 17 + kp];  // deg * bias term
#pragma unroll
        for (int jj = 0; jj < 4; ++jj) {
            int j = (((jj + 2 * h) & 3) << 2);   // j-phase rotated per half (banks)
            float4 wv = *(const float4*)(w + j);
            acc += Gk[j] * wv.x + Gk[j + 1] * wv.y + Gk[j + 2] * wv.z + Gk[j + 3] * wv.w;
        }
        T[i] = acc;
    }
#pragma unroll
    for (int msk = 1; msk <= 8; msk <<= 1) {
#pragma unroll
        for (int i = 0; i < 8; ++i) T[i] += __shfl_xor(T[i], msk);
    }
    float tmine  = T[k & 7];
    float tother = __shfl_xor(tmine, 16);
    float a_sum  = ((k >> 3) == h) ? tmine : tother;
    float invd   = 1.0f / (float)(deg > 0 ? deg : 1);
    float a_k    = a_sum * invd;

    // ---- node update (both halves compute; half 0 stores) ----
    float o[16];
#pragma unroll
    for (int d = 0; d < 16; d += 4) {
        float4 v = *(const float4*)(cur + n * 16 + d);  // broadcast
        o[d] = v.x; o[d + 1] = v.y; o[d + 2] = v.z; o[d + 3] = v.w;
    }
    float mcc = s_cb[k] + a_k;
#pragma unroll
    for (int d = 0; d < 16; ++d) mcc += o[d] * s_cr[d * 16 + k];
    float m = fmaxf(mcc, 0.0f);

    float ir = s_bi[k], iz = s_bi[16 + k], in_ = s_bi[32 + k];
    float hr = s_bh[k], hz = s_bh[16 + k], hh = s_bh[32 + k];
#pragma unroll
    for (int d = 0; d < 16; ++d) {
        float md = __shfl(m, d, 16);
        ir  += md * s_wiT[d * 48 + k];
        iz  += md * s_wiT[d * 48 + 16 + k];
        in_ += md * s_wiT[d * 48 + 32 + k];
        hr  += o[d] * s_whT[d * 48 + k];
        hz  += o[d] * s_whT[d * 48 + 16 + k];
        hh  += o[d] * s_whT[d * 48 + 32 + k];
    }
    float rg = 1.0f / (1.0f + __expf(-(ir + hr)));
    float z  = 1.0f / (1.0f + __expf(-(iz + hz)));
    float nh = tanhf(in_ + rg * hh);
    float hnew = (1.0f - z) * nh + z * o[k];

    if (h == 0) {
        if (last) out_final[n * 16 + k] = hnew;
        else      nxt[n * 16 + k] = hnew;
    }
}

extern "C" void kernel_launch(void* const* d_in, const int* in_sizes, int n_in,
                              void* d_out, int out_size, void* d_ws, size_t ws_size,
                              hipStream_t stream) {
    const float* x         = (const float*)d_in[0];
    const int*   ei        = (const int*)d_in[1];
    const float* edge_attr = (const float*)d_in[2];
    const float* lin0_w    = (const float*)d_in[3];
    const float* lin0_b    = (const float*)d_in[4];
    const float* nn1_w     = (const float*)d_in[5];
    const float* nn1_b     = (const float*)d_in[6];
    const float* nn2_w     = (const float*)d_in[7];
    const float* nn2_b     = (const float*)d_in[8];
    const float* conv_root = (const float*)d_in[9];
    const float* conv_bias = (const float*)d_in[10];
    const float* gru_w_ih  = (const float*)d_in[11];
    const float* gru_w_hh  = (const float*)d_in[12];
    const float* gru_b_ih  = (const float*)d_in[13];
    const float* gru_b_hh  = (const float*)d_in[14];
    float* out = (float*)d_out;

    k_setup<<<NN / 256, 256, 0, stream>>>(x, lin0_w, lin0_b);
    k_count<<<NE / 256, 256, 0, stream>>>(ei);
    k_scan<<<1, 256, 0, stream>>>();
    k_scatter<<<NE / 256, 256, 0, stream>>>(ei, edge_attr, nn1_w, nn1_b);

    for (int r = 0; r < 6; ++r) {
        k_round<<<NN / 8, 256, 0, stream>>>(nn2_w, nn2_b, conv_root, conv_bias,
                                            gru_w_ih, gru_w_hh, gru_b_ih, gru_b_hh,
                                            out, r & 1, r == 5 ? 1 : 0);
    }
}